// Round 8
// baseline (265.779 us; speedup 1.0000x reference)
//
#include <hip/hip_runtime.h>
#include <hip/hip_bf16.h>

// Problem constants
constexpr int B  = 128;
constexpr int C  = 235;
constexpr int N  = 21;
constexpr int HW = 4096;   // 64*64
constexpr int HO = 128;    // heads*fo
constexpr int E  = 41;     // 20 skeleton edges + 21 self loops

typedef __attribute__((ext_vector_type(8)))  short  short8;   // 8 bf16 (4 VGPRs)
typedef __attribute__((ext_vector_type(16))) float  f32x16;   // 32x32 accum
typedef __attribute__((ext_vector_type(4)))  float  f32x4;    // native vec4 for nt loads

__device__ inline unsigned short bf16r(float x) {
    return __bfloat16_as_ushort(__float2bfloat16(x));   // RNE
}

__device__ inline f32x4 ntload4(const float* p) {
    // non-temporal 16B load: f is streamed exactly once -> skip L3 allocation
    const f32x4* p4 = reinterpret_cast<const f32x4*>(p);
    return __builtin_nontemporal_load(p4);
}

// ---------------- K1: q[b,n,c] = sum_p t[b,n,p] * f[b,c,p] ----------------
// v7 = v4 (best structure: direct-from-global MFMA, wave owns two 32-col
// tiles, 1024 blocks) + NON-TEMPORAL f loads (f has zero reuse; if the
// ~3.3TB/s read cap is L3-fill throttling, nt loads bypass it).
constexpr int KSPLIT = 8;
constexpr int KRANGE = HW / KSPLIT;   // 512
constexpr int NSLOT  = KSPLIT;

__global__ __launch_bounds__(256) void k1_qgemm(
    const float* __restrict__ f,   // [B][C][HW]
    const float* __restrict__ t,   // [B][N][HW]
    float* __restrict__ qp)        // [NSLOT][B][N][C] partials
{
    const int b    = blockIdx.y;
    const int ks   = blockIdx.x;
    const int tid  = threadIdx.x;
    const int wave = tid >> 6;        // 0..3 -> N-tiles 2w, 2w+1
    const int lane = tid & 63;
    const int l31  = lane & 31;
    const int kh   = lane >> 5;       // k-half: 0 -> k 0..7, 1 -> k 8..15

    const float* fb = f + (size_t)b * C * HW;
    const float* tb = t + (size_t)b * N * HW;

    const int arow = (l31 < N) ? l31 : (N - 1);          // clamp pad rows
    const int c1   = wave * 64 + l31;                    // tile 2w
    const int c2   = wave * 64 + 32 + l31;               // tile 2w+1
    const int c1c  = (c1 < C) ? c1 : (C - 1);
    const int c2c  = (c2 < C) ? c2 : (C - 1);

    const float* pa = tb + (size_t)arow * HW + kh * 8;
    const float* p1 = fb + (size_t)c1c  * HW + kh * 8;
    const float* p2 = fb + (size_t)c2c  * HW + kh * 8;

    f32x16 acc0 = {};
    f32x16 acc1 = {};

    const int kend = ks * KRANGE + KRANGE;
    #pragma unroll 2
    for (int k = ks * KRANGE; k < kend; k += 16) {
        const float4 alo = *reinterpret_cast<const float4*>(pa + k);
        const float4 ahi = *reinterpret_cast<const float4*>(pa + k + 4);
        const f32x4 b1l = ntload4(p1 + k);
        const f32x4 b1h = ntload4(p1 + k + 4);
        const f32x4 b2l = ntload4(p2 + k);
        const f32x4 b2h = ntload4(p2 + k + 4);

        union { short8 v; unsigned short u[8]; } av, bv1, bv2;
        av.u[0]  = bf16r(alo.x); av.u[1]  = bf16r(alo.y);
        av.u[2]  = bf16r(alo.z); av.u[3]  = bf16r(alo.w);
        av.u[4]  = bf16r(ahi.x); av.u[5]  = bf16r(ahi.y);
        av.u[6]  = bf16r(ahi.z); av.u[7]  = bf16r(ahi.w);
        bv1.u[0] = bf16r(b1l[0]); bv1.u[1] = bf16r(b1l[1]);
        bv1.u[2] = bf16r(b1l[2]); bv1.u[3] = bf16r(b1l[3]);
        bv1.u[4] = bf16r(b1h[0]); bv1.u[5] = bf16r(b1h[1]);
        bv1.u[6] = bf16r(b1h[2]); bv1.u[7] = bf16r(b1h[3]);
        bv2.u[0] = bf16r(b2l[0]); bv2.u[1] = bf16r(b2l[1]);
        bv2.u[2] = bf16r(b2l[2]); bv2.u[3] = bf16r(b2l[3]);
        bv2.u[4] = bf16r(b2h[0]); bv2.u[5] = bf16r(b2h[1]);
        bv2.u[6] = bf16r(b2h[2]); bv2.u[7] = bf16r(b2h[3]);

        acc0 = __builtin_amdgcn_mfma_f32_32x32x16_bf16(av.v, bv1.v, acc0, 0, 0, 0);
        acc1 = __builtin_amdgcn_mfma_f32_32x32x16_bf16(av.v, bv2.v, acc1, 0, 0, 0);
    }

    // C/D layout (verified): col = lane&31, row = (reg&3) + 8*(reg>>2) + 4*(lane>>5)
    float* qpk = qp + ((size_t)ks * B + b) * N * C;
    #pragma unroll
    for (int reg = 0; reg < 16; reg++) {
        const int row = (reg & 3) + 8 * (reg >> 2) + 4 * kh;
        if (row < N) {
            if (c1 < C) qpk[row * C + c1] = acc0[reg];
            if (c2 < C) qpk[row * C + c2] = acc1[reg];
        }
    }
}

// ---------------- K1b: reduce partials -> q, plus per-(b,n) BN sums ----------------
__global__ __launch_bounds__(256) void k1b_bn(
    const float* __restrict__ qp,  // [NSLOT][B][N][C]
    float* __restrict__ q,         // [B][N][C]
    float* __restrict__ bnp)       // [N][B][2] partial {sum, sumsq}
{
    const int b    = blockIdx.x;
    const int tid  = threadIdx.x;
    const int wave = tid >> 6;
    const int lane = tid & 63;
    __shared__ float rs[N][4], rs2[N][4];
    constexpr int S = B * N * C;

    for (int n = 0; n < N; ++n) {
        float v = 0.f;
        const int idx = (b * N + n) * C + tid;
        if (tid < C) {
            #pragma unroll
            for (int p = 0; p < NSLOT; p++) v += qp[(size_t)p * S + idx];
            q[idx] = v;
        }
        float s = v, s2 = v * v;
        for (int off = 32; off; off >>= 1) {
            s  += __shfl_down(s,  off);
            s2 += __shfl_down(s2, off);
        }
        if (lane == 0) { rs[n][wave] = s; rs2[n][wave] = s2; }
    }
    __syncthreads();
    if (tid < N) {
        const float S1 = rs[tid][0] + rs[tid][1] + rs[tid][2] + rs[tid][3];
        const float S2 = rs2[tid][0] + rs2[tid][1] + rs2[tid][2] + rs2[tid][3];
        bnp[(tid * B + b) * 2]     = S1;   // [N][B][2] layout for coalesced k3 read
        bnp[(tid * B + b) * 2 + 1] = S2;
    }
}

// ---------------- K3: stats + BN-apply + LeakyReLU + GAT + Cheb ----------------
__global__ __launch_bounds__(256) void k3_tail(
    const float* __restrict__ q,        // [B][N][C]
    const float* __restrict__ bnp,      // [N][B][2]
    const float* __restrict__ gamma,    // [N]
    const float* __restrict__ beta,     // [N]
    const float* __restrict__ gatw,     // [C][HO]
    const float* __restrict__ attsrc,   // [4][32]
    const float* __restrict__ attdst,   // [4][32]
    const float* __restrict__ gatbias,  // [HO]
    const float* __restrict__ chebw,    // [2][HO][3]
    const float* __restrict__ chebbias, // [3]
    const float* __restrict__ adj,      // [N][N]
    const int* __restrict__ esrc,
    const int* __restrict__ edst,
    float* __restrict__ out)            // [B][N][3]
{
    __shared__ float ql[N][C + 1];
    __shared__ float Wl[48][HO];
    __shared__ float hl[N][HO];
    __shared__ float xl[N][HO];
    __shared__ float stl[N][2];
    __shared__ float asrcl[N][4], adstl[N][4];
    __shared__ float el[E][4], alphal[E][4];
    __shared__ float mx[N][4], den[N][4];
    __shared__ float zl[N][3], t0l[N][3], dsl[N];
    __shared__ int esl[E], edl[E];

    const int b = blockIdx.x;
    const int tid = threadIdx.x;

    // finalize BN stats: thread-groups of 12 reduce one n over B=128
    {
        const int n = tid / 12, sub = tid % 12;   // 252 threads cover 21 n
        float S1 = 0.f, S2 = 0.f;
        if (n < N) {
            for (int bb = sub; bb < B; bb += 12) {
                S1 += bnp[(n * B + bb) * 2];
                S2 += bnp[(n * B + bb) * 2 + 1];
            }
        }
        __shared__ float g1[N][12], g2[N][12];
        if (n < N) { g1[n][sub] = S1; g2[n][sub] = S2; }
        __syncthreads();
        if (tid < N) {
            float a1 = 0.f, a2 = 0.f;
            for (int s = 0; s < 12; s++) { a1 += g1[tid][s]; a2 += g2[tid][s]; }
            const float cnt  = (float)(B * C);
            const float mean = a1 / cnt;
            const float var  = a2 / cnt - mean * mean;
            const float sc   = gamma[tid] * rsqrtf(var + 1e-5f);
            stl[tid][0] = sc;
            stl[tid][1] = beta[tid] - mean * sc;
        }
    }
    if (tid < E) { esl[tid] = esrc[tid]; edl[tid] = edst[tid]; }
    __syncthreads();

    for (int v = tid; v < N * C; v += 256) {
        const int n = v / C, c = v % C;
        float x = q[((size_t)b * N + n) * C + c];
        x = x * stl[n][0] + stl[n][1];
        ql[n][c] = (x >= 0.f) ? x : 0.1f * x;
    }
    for (int v = tid; v < N * HO; v += 256) hl[v >> 7][v & 127] = 0.f;
    __syncthreads();

    for (int k0 = 0; k0 < C; k0 += 48) {
        const int kc = (C - k0) < 48 ? (C - k0) : 48;
        for (int v = tid; v < kc * HO; v += 256) {
            const int kk = v >> 7, o = v & 127;
            Wl[kk][o] = gatw[(size_t)(k0 + kk) * HO + o];
        }
        __syncthreads();
        for (int idx = tid; idx < N * HO; idx += 256) {
            const int n = idx >> 7, o = idx & 127;
            float s = hl[n][o];
            for (int kk = 0; kk < kc; kk++)
                s += ql[n][k0 + kk] * Wl[kk][o];
            hl[n][o] = s;
        }
        __syncthreads();
    }

    if (tid < N * 4) {
        const int n = tid >> 2, h = tid & 3;
        float ss = 0.f, sd = 0.f;
        for (int fo = 0; fo < 32; fo++) {
            const float hv = hl[n][h * 32 + fo];
            ss += hv * attsrc[h * 32 + fo];
            sd += hv * attdst[h * 32 + fo];
        }
        asrcl[n][h] = ss; adstl[n][h] = sd;
    }
    __syncthreads();
    if (tid < E * 4) {
        const int e = tid >> 2, h = tid & 3;
        const float v = asrcl[esl[e]][h] + adstl[edl[e]][h];
        el[e][h] = (v >= 0.f) ? v : 0.2f * v;
    }
    __syncthreads();
    if (tid < N * 4) {
        const int n = tid >> 2, h = tid & 3;
        float m = -1e30f;
        for (int e = 0; e < E; e++)
            if (edl[e] == n) m = fmaxf(m, el[e][h]);
        mx[n][h] = m;
    }
    __syncthreads();
    if (tid < E * 4) {
        const int e = tid >> 2, h = tid & 3;
        el[e][h] = __expf(el[e][h] - mx[edl[e]][h]);
    }
    __syncthreads();
    if (tid < N * 4) {
        const int n = tid >> 2, h = tid & 3;
        float s = 0.f;
        for (int e = 0; e < E; e++)
            if (edl[e] == n) s += el[e][h];
        den[n][h] = s;
    }
    __syncthreads();
    if (tid < E * 4) {
        const int e = tid >> 2, h = tid & 3;
        alphal[e][h] = el[e][h] / den[edl[e]][h];
    }
    __syncthreads();

    for (int idx = tid; idx < N * HO; idx += 256) {
        const int n = idx >> 7, o = idx & 127, h = o >> 5;
        float s = 0.f;
        for (int e = 0; e < E; e++)
            if (edl[e] == n) s += alphal[e][h] * hl[esl[e]][o];
        xl[n][o] = s + gatbias[o];
    }
    if (tid < N) {
        float s = 0.f;
        for (int j2 = 0; j2 < N; j2++) s += adj[tid * N + j2];
        dsl[tid] = rsqrtf(s);
    }
    __syncthreads();

    if (tid < N * 3) {
        const int n = tid / 3, o = tid % 3;
        float s0 = 0.f, sz = 0.f;
        for (int c2 = 0; c2 < HO; c2++) {
            const float xv = xl[n][c2];
            s0 += xv * chebw[(size_t)c2 * 3 + o];
            sz += xv * chebw[(size_t)(HO + c2) * 3 + o];
        }
        t0l[n][o] = s0; zl[n][o] = sz;
    }
    __syncthreads();
    if (tid < N * 3) {
        const int m = tid / 3, o = tid % 3;
        float s = t0l[m][o] + zl[m][o];
        for (int n2 = 0; n2 < N; n2++)
            s -= dsl[m] * adj[m * N + n2] * dsl[n2] * zl[n2][o];
        out[(size_t)b * N * 3 + tid] = s + chebbias[o];
    }
}

extern "C" void kernel_launch(void* const* d_in, const int* in_sizes, int n_in,
                              void* d_out, int out_size, void* d_ws, size_t ws_size,
                              hipStream_t stream) {
    const float* feature  = (const float*)d_in[0];
    const float* target   = (const float*)d_in[1];
    const float* gamma    = (const float*)d_in[2];
    const float* beta     = (const float*)d_in[3];
    const float* gatw     = (const float*)d_in[4];
    const float* attsrc   = (const float*)d_in[5];
    const float* attdst   = (const float*)d_in[6];
    const float* gatbias  = (const float*)d_in[7];
    const float* chebw    = (const float*)d_in[8];
    const float* chebbias = (const float*)d_in[9];
    const float* adj      = (const float*)d_in[10];
    const int*   esrc     = (const int*)d_in[11];
    const int*   edst     = (const int*)d_in[12];

    constexpr int QS = B * N * C;
    float* qp  = (float*)d_ws;                 // [NSLOT][B][N][C]
    float* q   = qp + (size_t)NSLOT * QS;      // [B][N][C]
    float* bnp = q + QS;                       // [N][B][2]
    float* out = (float*)d_out;

    hipLaunchKernelGGL(k1_qgemm, dim3(KSPLIT, B), dim3(256), 0, stream,
                       feature, target, qp);
    hipLaunchKernelGGL(k1b_bn, dim3(B), dim3(256), 0, stream, qp, q, bnp);
    hipLaunchKernelGGL(k3_tail, dim3(B), dim3(256), 0, stream,
                       q, bnp, gamma, beta, gatw, attsrc, attdst, gatbias,
                       chebw, chebbias, adj, esrc, edst, out);
}

// Round 9
// 192.062 us; speedup vs baseline: 1.3838x; 1.3838x over previous
//
#include <hip/hip_runtime.h>
#include <hip/hip_bf16.h>

// Problem constants
constexpr int B  = 128;
constexpr int C  = 235;
constexpr int N  = 21;
constexpr int HW = 4096;   // 64*64
constexpr int HO = 128;    // heads*fo
constexpr int E  = 41;     // 20 skeleton edges + 21 self loops

typedef __attribute__((ext_vector_type(8)))  short  short8;   // 8 bf16 (4 VGPRs)
typedef __attribute__((ext_vector_type(16))) float  f32x16;   // 32x32 accum

__device__ inline unsigned short bf16r(float x) {
    return __bfloat16_as_ushort(__float2bfloat16(x));   // RNE
}

// ---------------- K1: q[b,n,c] = sum_p t[b,n,p] * f[b,c,p] ----------------
// v4 exact (best measured: ~165us, at the ~3.3TB/s read-path roofline).
// Direct-from-global MFMA, wave owns two 32-col tiles, 1024 blocks.
constexpr int KSPLIT = 8;
constexpr int KRANGE = HW / KSPLIT;   // 512
constexpr int NSLOT  = KSPLIT;

__global__ __launch_bounds__(256) void k1_qgemm(
    const float* __restrict__ f,   // [B][C][HW]
    const float* __restrict__ t,   // [B][N][HW]
    float* __restrict__ qp)        // [NSLOT][B][N][C] partials
{
    const int b    = blockIdx.y;
    const int ks   = blockIdx.x;
    const int tid  = threadIdx.x;
    const int wave = tid >> 6;        // 0..3 -> N-tiles 2w, 2w+1
    const int lane = tid & 63;
    const int l31  = lane & 31;
    const int kh   = lane >> 5;       // k-half: 0 -> k 0..7, 1 -> k 8..15

    const float* fb = f + (size_t)b * C * HW;
    const float* tb = t + (size_t)b * N * HW;

    const int arow = (l31 < N) ? l31 : (N - 1);          // clamp pad rows
    const int c1   = wave * 64 + l31;                    // tile 2w
    const int c2   = wave * 64 + 32 + l31;               // tile 2w+1
    const int c1c  = (c1 < C) ? c1 : (C - 1);
    const int c2c  = (c2 < C) ? c2 : (C - 1);

    const float* pa = tb + (size_t)arow * HW + kh * 8;
    const float* p1 = fb + (size_t)c1c  * HW + kh * 8;
    const float* p2 = fb + (size_t)c2c  * HW + kh * 8;

    f32x16 acc0 = {};
    f32x16 acc1 = {};

    const int kend = ks * KRANGE + KRANGE;
    #pragma unroll 2
    for (int k = ks * KRANGE; k < kend; k += 16) {
        const float4 alo = *reinterpret_cast<const float4*>(pa + k);
        const float4 ahi = *reinterpret_cast<const float4*>(pa + k + 4);
        const float4 b1l = *reinterpret_cast<const float4*>(p1 + k);
        const float4 b1h = *reinterpret_cast<const float4*>(p1 + k + 4);
        const float4 b2l = *reinterpret_cast<const float4*>(p2 + k);
        const float4 b2h = *reinterpret_cast<const float4*>(p2 + k + 4);

        union { short8 v; unsigned short u[8]; } av, bv1, bv2;
        av.u[0]  = bf16r(alo.x); av.u[1]  = bf16r(alo.y);
        av.u[2]  = bf16r(alo.z); av.u[3]  = bf16r(alo.w);
        av.u[4]  = bf16r(ahi.x); av.u[5]  = bf16r(ahi.y);
        av.u[6]  = bf16r(ahi.z); av.u[7]  = bf16r(ahi.w);
        bv1.u[0] = bf16r(b1l.x); bv1.u[1] = bf16r(b1l.y);
        bv1.u[2] = bf16r(b1l.z); bv1.u[3] = bf16r(b1l.w);
        bv1.u[4] = bf16r(b1h.x); bv1.u[5] = bf16r(b1h.y);
        bv1.u[6] = bf16r(b1h.z); bv1.u[7] = bf16r(b1h.w);
        bv2.u[0] = bf16r(b2l.x); bv2.u[1] = bf16r(b2l.y);
        bv2.u[2] = bf16r(b2l.z); bv2.u[3] = bf16r(b2l.w);
        bv2.u[4] = bf16r(b2h.x); bv2.u[5] = bf16r(b2h.y);
        bv2.u[6] = bf16r(b2h.z); bv2.u[7] = bf16r(b2h.w);

        acc0 = __builtin_amdgcn_mfma_f32_32x32x16_bf16(av.v, bv1.v, acc0, 0, 0, 0);
        acc1 = __builtin_amdgcn_mfma_f32_32x32x16_bf16(av.v, bv2.v, acc1, 0, 0, 0);
    }

    // C/D layout (verified): col = lane&31, row = (reg&3) + 8*(reg>>2) + 4*(lane>>5)
    float* qpk = qp + ((size_t)ks * B + b) * N * C;
    #pragma unroll
    for (int reg = 0; reg < 16; reg++) {
        const int row = (reg & 3) + 8 * (reg >> 2) + 4 * kh;
        if (row < N) {
            if (c1 < C) qpk[row * C + c1] = acc0[reg];
            if (c2 < C) qpk[row * C + c2] = acc1[reg];
        }
    }
}

// ---------------- K1b: reduce partials -> q, plus per-(b,n) BN sums ----------------
// grid (B, 2): ngrp 0 handles n 0..10, ngrp 1 handles n 11..20.
__global__ __launch_bounds__(256) void k1b_bn(
    const float* __restrict__ qp,  // [NSLOT][B][N][C]
    float* __restrict__ q,         // [B][N][C]
    float* __restrict__ bnp)       // [N][B][2] partial {sum, sumsq}
{
    const int b    = blockIdx.x;
    const int ngrp = blockIdx.y;
    const int n0   = ngrp ? 11 : 0;
    const int ncnt = ngrp ? 10 : 11;
    const int tid  = threadIdx.x;
    const int wave = tid >> 6;
    const int lane = tid & 63;
    __shared__ float rs[11][4], rs2[11][4];
    constexpr int S = B * N * C;

    for (int i = 0; i < ncnt; ++i) {
        const int n = n0 + i;
        float v = 0.f;
        const int idx = (b * N + n) * C + tid;
        if (tid < C) {
            #pragma unroll
            for (int p = 0; p < NSLOT; p++) v += qp[(size_t)p * S + idx];
            q[idx] = v;
        }
        float s = v, s2 = v * v;
        for (int off = 32; off; off >>= 1) {
            s  += __shfl_down(s,  off);
            s2 += __shfl_down(s2, off);
        }
        if (lane == 0) { rs[i][wave] = s; rs2[i][wave] = s2; }
    }
    __syncthreads();
    if (tid < ncnt) {
        const float S1 = rs[tid][0] + rs[tid][1] + rs[tid][2] + rs[tid][3];
        const float S2 = rs2[tid][0] + rs2[tid][1] + rs2[tid][2] + rs2[tid][3];
        bnp[((n0 + tid) * B + b) * 2]     = S1;
        bnp[((n0 + tid) * B + b) * 2 + 1] = S2;
    }
}

// ---------------- K3: stats + BN-apply + LeakyReLU + GAT + Cheb ----------------
__global__ __launch_bounds__(256) void k3_tail(
    const float* __restrict__ q,        // [B][N][C]
    const float* __restrict__ bnp,      // [N][B][2]
    const float* __restrict__ gamma,    // [N]
    const float* __restrict__ beta,     // [N]
    const float* __restrict__ gatw,     // [C][HO]
    const float* __restrict__ attsrc,   // [4][32]
    const float* __restrict__ attdst,   // [4][32]
    const float* __restrict__ gatbias,  // [HO]
    const float* __restrict__ chebw,    // [2][HO][3]
    const float* __restrict__ chebbias, // [3]
    const float* __restrict__ adj,      // [N][N]
    const int* __restrict__ esrc,
    const int* __restrict__ edst,
    float* __restrict__ out)            // [B][N][3]
{
    __shared__ float ql[N][C + 1];
    __shared__ float Wl[48][HO];
    __shared__ float hl[N][HO];
    __shared__ float xl[N][HO];
    __shared__ float stl[N][2];
    __shared__ float asrcl[N][4], adstl[N][4];
    __shared__ float el[E][4], alphal[E][4];
    __shared__ float mx[N][4], den[N][4];
    __shared__ float zl[N][3], t0l[N][3], dsl[N];
    __shared__ int esl[E], edl[E];

    const int b = blockIdx.x;
    const int tid = threadIdx.x;

    // finalize BN stats: thread-groups of 12 reduce one n over B=128
    {
        const int n = tid / 12, sub = tid % 12;   // 252 threads cover 21 n
        float S1 = 0.f, S2 = 0.f;
        if (n < N) {
            for (int bb = sub; bb < B; bb += 12) {
                S1 += bnp[(n * B + bb) * 2];
                S2 += bnp[(n * B + bb) * 2 + 1];
            }
        }
        __shared__ float g1[N][12], g2[N][12];
        if (n < N) { g1[n][sub] = S1; g2[n][sub] = S2; }
        __syncthreads();
        if (tid < N) {
            float a1 = 0.f, a2 = 0.f;
            for (int s = 0; s < 12; s++) { a1 += g1[tid][s]; a2 += g2[tid][s]; }
            const float cnt  = (float)(B * C);
            const float mean = a1 / cnt;
            const float var  = a2 / cnt - mean * mean;
            const float sc   = gamma[tid] * rsqrtf(var + 1e-5f);
            stl[tid][0] = sc;
            stl[tid][1] = beta[tid] - mean * sc;
        }
    }
    if (tid < E) { esl[tid] = esrc[tid]; edl[tid] = edst[tid]; }
    __syncthreads();

    for (int v = tid; v < N * C; v += 256) {
        const int n = v / C, c = v % C;
        float x = q[((size_t)b * N + n) * C + c];
        x = x * stl[n][0] + stl[n][1];
        ql[n][c] = (x >= 0.f) ? x : 0.1f * x;
    }
    __syncthreads();

    // h = ql @ gat_w: thread owns one o (tid&127) and an n-group
    // (tid>>7: 0 -> n 0..10, 1 -> n 11..20). Register accumulators;
    // one Wl read per (kk,o), ql reads broadcast across the 128-thread group.
    {
        const int o   = tid & 127;
        const int g   = tid >> 7;
        const int n0g = g ? 11 : 0;
        const int ng  = g ? 10 : 11;
        float acc[11] = {};
        for (int k0 = 0; k0 < C; k0 += 48) {
            const int kc = (C - k0) < 48 ? (C - k0) : 48;
            for (int v = tid; v < kc * HO; v += 256) {
                const int kk = v >> 7, oo = v & 127;
                Wl[kk][oo] = gatw[(size_t)(k0 + kk) * HO + oo];
            }
            __syncthreads();
            for (int kk = 0; kk < kc; kk++) {
                const float w = Wl[kk][o];
                #pragma unroll
                for (int i = 0; i < 11; i++) {
                    if (i < ng)
                        acc[i] += ql[n0g + i][k0 + kk] * w;
                }
            }
            __syncthreads();
        }
        for (int i = 0; i < ng; i++)
            hl[n0g + i][o] = acc[i];
    }
    __syncthreads();

    if (tid < N * 4) {
        const int n = tid >> 2, h = tid & 3;
        float ss = 0.f, sd = 0.f;
        for (int fo = 0; fo < 32; fo++) {
            const float hv = hl[n][h * 32 + fo];
            ss += hv * attsrc[h * 32 + fo];
            sd += hv * attdst[h * 32 + fo];
        }
        asrcl[n][h] = ss; adstl[n][h] = sd;
    }
    __syncthreads();
    if (tid < E * 4) {
        const int e = tid >> 2, h = tid & 3;
        const float v = asrcl[esl[e]][h] + adstl[edl[e]][h];
        el[e][h] = (v >= 0.f) ? v : 0.2f * v;
    }
    __syncthreads();
    if (tid < N * 4) {
        const int n = tid >> 2, h = tid & 3;
        float m = -1e30f;
        for (int e = 0; e < E; e++)
            if (edl[e] == n) m = fmaxf(m, el[e][h]);
        mx[n][h] = m;
    }
    __syncthreads();
    if (tid < E * 4) {
        const int e = tid >> 2, h = tid & 3;
        el[e][h] = __expf(el[e][h] - mx[edl[e]][h]);
    }
    __syncthreads();
    if (tid < N * 4) {
        const int n = tid >> 2, h = tid & 3;
        float s = 0.f;
        for (int e = 0; e < E; e++)
            if (edl[e] == n) s += el[e][h];
        den[n][h] = s;
    }
    __syncthreads();
    if (tid < E * 4) {
        const int e = tid >> 2, h = tid & 3;
        alphal[e][h] = el[e][h] / den[edl[e]][h];
    }
    __syncthreads();

    for (int idx = tid; idx < N * HO; idx += 256) {
        const int n = idx >> 7, o = idx & 127, h = o >> 5;
        float s = 0.f;
        for (int e = 0; e < E; e++)
            if (edl[e] == n) s += alphal[e][h] * hl[esl[e]][o];
        xl[n][o] = s + gatbias[o];
    }
    if (tid < N) {
        float s = 0.f;
        for (int j2 = 0; j2 < N; j2++) s += adj[tid * N + j2];
        dsl[tid] = rsqrtf(s);
    }
    __syncthreads();

    if (tid < N * 3) {
        const int n = tid / 3, o = tid % 3;
        float s0 = 0.f, sz = 0.f;
        for (int c2 = 0; c2 < HO; c2++) {
            const float xv = xl[n][c2];
            s0 += xv * chebw[(size_t)c2 * 3 + o];
            sz += xv * chebw[(size_t)(HO + c2) * 3 + o];
        }
        t0l[n][o] = s0; zl[n][o] = sz;
    }
    __syncthreads();
    if (tid < N * 3) {
        const int m = tid / 3, o = tid % 3;
        float s = t0l[m][o] + zl[m][o];
        for (int n2 = 0; n2 < N; n2++)
            s -= dsl[m] * adj[m * N + n2] * dsl[n2] * zl[n2][o];
        out[(size_t)b * N * 3 + tid] = s + chebbias[o];
    }
}

extern "C" void kernel_launch(void* const* d_in, const int* in_sizes, int n_in,
                              void* d_out, int out_size, void* d_ws, size_t ws_size,
                              hipStream_t stream) {
    const float* feature  = (const float*)d_in[0];
    const float* target   = (const float*)d_in[1];
    const float* gamma    = (const float*)d_in[2];
    const float* beta     = (const float*)d_in[3];
    const float* gatw     = (const float*)d_in[4];
    const float* attsrc   = (const float*)d_in[5];
    const float* attdst   = (const float*)d_in[6];
    const float* gatbias  = (const float*)d_in[7];
    const float* chebw    = (const float*)d_in[8];
    const float* chebbias = (const float*)d_in[9];
    const float* adj      = (const float*)d_in[10];
    const int*   esrc     = (const int*)d_in[11];
    const int*   edst     = (const int*)d_in[12];

    constexpr int QS = B * N * C;
    float* qp  = (float*)d_ws;                 // [NSLOT][B][N][C]
    float* q   = qp + (size_t)NSLOT * QS;      // [B][N][C]
    float* bnp = q + QS;                       // [N][B][2]
    float* out = (float*)d_out;

    hipLaunchKernelGGL(k1_qgemm, dim3(KSPLIT, B), dim3(256), 0, stream,
                       feature, target, qp);
    hipLaunchKernelGGL(k1b_bn, dim3(B, 2), dim3(256), 0, stream, qp, q, bnp);
    hipLaunchKernelGGL(k3_tail, dim3(B), dim3(256), 0, stream,
                       q, bnp, gamma, beta, gatw, attsrc, attdst, gatbias,
                       chebw, chebbias, adj, esrc, edst, out);
}